// Round 7
// baseline (135.049 us; speedup 1.0000x reference)
//
#include <hip/hip_runtime.h>

#define T_TOTAL 200000
#define NL 49
#define NP 50
#define NB 20
#define THREADS 256
#define WPB (THREADS / 64)                      // waves per block = 4
#define CHUNK 16                                // timesteps per wave
#define HALF (CHUNK / 2)                        // per-stream length = 8
#define NWAVES (T_TOTAL / CHUNK)                // 12500 (exact)
#define NBLOCKS ((NWAVES + WPB - 1) / WPB)      // 3125

// Wave-per-timestep register tree-prefix (9 ds_bpermute per t), with TWO
// independent timestep streams per wave for 2x memory-level parallelism.
// Stream A = [t0, t0+8), stream B = [t0+8, t0+16). A's temporal-diff halo
// (t0+8) is B's first iterate (register reuse); only B needs a halo compute.
__global__ __launch_bounds__(THREADS, 8) void bbf_fused(
    const float* __restrict__ lines,
    const float* __restrict__ rootsx,
    const float* __restrict__ rootsy,
    const float* __restrict__ rootsz,
    const float* __restrict__ ax,
    const float* __restrict__ ay,
    const float* __restrict__ az,
    const float* __restrict__ tarx,
    const float* __restrict__ tary,
    const float* __restrict__ w,
    float* __restrict__ outx,
    float* __restrict__ outy,
    float* __restrict__ outz,
    double* __restrict__ partials)   // [NBLOCKS][2]
{
    __shared__ double redL[WPB], redR[WPB];

    const int tid  = threadIdx.x;
    const int lane = tid & 63;
    const int wv   = tid >> 6;
    const int gw   = blockIdx.x * WPB + wv;
    const int t0   = gw * CHUNK;

    const bool isNode = (lane < NP);
    const bool isLimb = (lane >= 1 && lane < NP);

    float Lv = 0.f;
    if (isLimb) Lv = expf(lines[(lane - 1) % NB]);

    // ancestor jump table (pointer jumping: 1st, 2nd, 4th ancestor)
    const int a1 = isLimb ? ((lane - 1) >> 1) : 0;
    const int a2 = (a1 > 0) ? ((a1 - 1) >> 1) : 0;
    const int a3 = (a2 > 0) ? ((a2 - 1) >> 1) : 0;
    const int a4 = (a3 > 0) ? ((a3 - 1) >> 1) : 0;

    float lossAcc = 0.f, regAcc = 0.f;
    float pxA, pyA, pzA, pxB, pyB, pzB;          // previous positions per stream
    float fxB = 0.f, fyB = 0.f, fzB = 0.f;       // B's first position (= A's halo)

#pragma unroll 2
    for (int i = 0; i < HALF; ++i) {
        const int tA = t0 + i;
        const int tB = tA + HALF;

        // ---- issue all independent loads up front (2 streams) ----
        float xA = 0.f, yA = 0.f, zA = 0.f, xB = 0.f, yB = 0.f, zB = 0.f;
        if (isLimb) {
            const size_t giA = (size_t)tA * NL + (lane - 1);
            const size_t giB = (size_t)tB * NL + (lane - 1);
            xA = ax[giA]; yA = ay[giA]; zA = az[giA];
            xB = ax[giB]; yB = ay[giB]; zB = az[giB];
        }
        const size_t goA = (size_t)tA * NP + lane;
        const size_t goB = (size_t)tB * NP + lane;
        float txA = 0.f, tyA = 0.f, wvA = 0.f, txB = 0.f, tyB = 0.f, wvB = 0.f;
        if (isNode) {
            txA = tarx[goA]; tyA = tary[goA]; wvA = w[goA];
            txB = tarx[goB]; tyB = tary[goB]; wvB = w[goB];
        }
        const int tAu = __builtin_amdgcn_readfirstlane(tA);
        const int tBu = __builtin_amdgcn_readfirstlane(tB);
        const float rxA = rootsx[tAu], ryA = rootsy[tAu], rzA = rootsz[tAu];
        const float rxB = rootsx[tBu], ryB = rootsy[tBu], rzB = rootsz[tBu];

        // ---- stream A: delta + register prefix ----
        float dxA = 0.f, dyA = 0.f, dzA = 0.f;
        if (isLimb) {
            const float n = sqrtf(xA * xA + yA * yA + zA * zA) + 1e-10f;
            const float s = Lv / n;
            dxA = xA * s; dyA = yA * s; dzA = zA * s;
        }
        dxA += __shfl(dxA, a1); dyA += __shfl(dyA, a1); dzA += __shfl(dzA, a1);
        dxA += __shfl(dxA, a2); dyA += __shfl(dyA, a2); dzA += __shfl(dzA, a2);
        dxA += __shfl(dxA, a4); dyA += __shfl(dyA, a4); dzA += __shfl(dzA, a4);
        const float XA = dxA + rxA, YA = dyA + ryA, ZA = dzA + rzA;

        // ---- stream B: delta + register prefix (independent chain) ----
        float dxB = 0.f, dyB = 0.f, dzB = 0.f;
        if (isLimb) {
            const float n = sqrtf(xB * xB + yB * yB + zB * zB) + 1e-10f;
            const float s = Lv / n;
            dxB = xB * s; dyB = yB * s; dzB = zB * s;
        }
        dxB += __shfl(dxB, a1); dyB += __shfl(dyB, a1); dzB += __shfl(dzB, a1);
        dxB += __shfl(dxB, a2); dyB += __shfl(dyB, a2); dzB += __shfl(dzB, a2);
        dxB += __shfl(dxB, a4); dyB += __shfl(dyB, a4); dzB += __shfl(dzB, a4);
        const float XB = dxB + rxB, YB = dyB + ryB, ZB = dzB + rzB;

        // ---- outputs + loss ----
        if (isNode) {
            outx[goA] = XA; outy[goA] = YA; outz[goA] = ZA;
            outx[goB] = XB; outy[goB] = YB; outz[goB] = ZB;
            const float e1 = XA - txA, e2 = YA - tyA;
            lossAcc += wvA * (e1 * e1 + e2 * e2);
            const float e3 = XB - txB, e4 = YB - tyB;
            lossAcc += wvB * (e3 * e3 + e4 * e4);
        }

        // ---- temporal reg2 pairs ----
        if (i == 0) {
            fxB = XB; fyB = YB; fzB = ZB;
        } else if (isNode) {
            float d1 = pxA - XA, d2 = pyA - YA, d3 = pzA - ZA;
            regAcc += d1 * d1 + d2 * d2 + d3 * d3;
            d1 = pxB - XB; d2 = pyB - YB; d3 = pzB - ZB;
            regAcc += d1 * d1 + d2 * d2 + d3 * d3;
        }
        pxA = XA; pyA = YA; pzA = ZA;
        pxB = XB; pyB = YB; pzB = ZB;
    }

    // cross pair (t0+7, t0+8): A's last vs B's first (register reuse, no halo)
    if (isNode) {
        const float d1 = pxA - fxB, d2 = pyA - fyB, d3 = pzA - fzB;
        regAcc += d1 * d1 + d2 * d2 + d3 * d3;
    }

    // B halo pair (t0+15, t0+16) — skip for the last wave (t0+16 == T)
    const int tH = t0 + CHUNK;
    if (tH < T_TOTAL) {
        float xH = 0.f, yH = 0.f, zH = 0.f;
        if (isLimb) {
            const size_t gi = (size_t)tH * NL + (lane - 1);
            xH = ax[gi]; yH = ay[gi]; zH = az[gi];
        }
        float dxH = 0.f, dyH = 0.f, dzH = 0.f;
        if (isLimb) {
            const float n = sqrtf(xH * xH + yH * yH + zH * zH) + 1e-10f;
            const float s = Lv / n;
            dxH = xH * s; dyH = yH * s; dzH = zH * s;
        }
        dxH += __shfl(dxH, a1); dyH += __shfl(dyH, a1); dzH += __shfl(dzH, a1);
        dxH += __shfl(dxH, a2); dyH += __shfl(dyH, a2); dzH += __shfl(dzH, a2);
        dxH += __shfl(dxH, a4); dyH += __shfl(dyH, a4); dzH += __shfl(dzH, a4);
        const int tHu = __builtin_amdgcn_readfirstlane(tH);
        const float XH = dxH + rootsx[tHu];
        const float YH = dyH + rootsy[tHu];
        const float ZH = dzH + rootsz[tHu];
        if (isNode) {
            const float d1 = pxB - XH, d2 = pyB - YH, d3 = pzB - ZH;
            regAcc += d1 * d1 + d2 * d2 + d3 * d3;
        }
    }

    // wave reduce -> cross-wave LDS -> per-block partial
    for (int off = 32; off > 0; off >>= 1) {
        lossAcc += __shfl_down(lossAcc, off);
        regAcc  += __shfl_down(regAcc, off);
    }
    if (lane == 0) { redL[wv] = (double)lossAcc; redR[wv] = (double)regAcc; }
    __syncthreads();
    if (tid == 0) {
        double l = 0.0, r = 0.0;
        for (int i = 0; i < WPB; ++i) { l += redL[i]; r += redR[i]; }
        partials[2 * (size_t)blockIdx.x]     = l;
        partials[2 * (size_t)blockIdx.x + 1] = r;
    }
}

__global__ __launch_bounds__(256) void bbf_finalize(
    const float* __restrict__ lines,
    const double* __restrict__ partials,
    float* __restrict__ out_total)
{
    __shared__ double rl[4], rr[4];
    const int tid = threadIdx.x;
    double l = 0.0, r = 0.0;
    for (int i = tid; i < NBLOCKS; i += 256) {
        l += partials[2 * (size_t)i];
        r += partials[2 * (size_t)i + 1];
    }
    for (int off = 32; off > 0; off >>= 1) {
        l += __shfl_down(l, off);
        r += __shfl_down(r, off);
    }
    const int wid = tid >> 6;
    if ((tid & 63) == 0) { rl[wid] = l; rr[wid] = r; }
    __syncthreads();
    if (tid == 0) {
        double L = 0.0, R = 0.0;
        for (int i = 0; i < 4; ++i) { L += rl[i]; R += rr[i]; }
        double reg1 = 0.0;
        for (int i = 0; i < NB; ++i) reg1 += (double)expf(lines[i]);
        const double loss = L / ((double)T_TOTAL * (double)NP);
        const double reg2 = R / ((double)(T_TOTAL - 1) * (double)NP);
        *out_total = (float)(loss + 0.001 * reg1 + 0.1 * reg2);
    }
}

extern "C" void kernel_launch(void* const* d_in, const int* in_sizes, int n_in,
                              void* d_out, int out_size, void* d_ws, size_t ws_size,
                              hipStream_t stream) {
    const float* lines  = (const float*)d_in[0];
    const float* rootsx = (const float*)d_in[1];
    const float* rootsy = (const float*)d_in[2];
    const float* rootsz = (const float*)d_in[3];
    const float* ax     = (const float*)d_in[4];
    const float* ay     = (const float*)d_in[5];
    const float* az     = (const float*)d_in[6];
    const float* tarx   = (const float*)d_in[7];
    const float* tary   = (const float*)d_in[8];
    const float* w      = (const float*)d_in[9];

    float* out = (float*)d_out;
    const size_t plane = (size_t)T_TOTAL * NP;
    float* outx = out;
    float* outy = out + plane;
    float* outz = out + 2 * plane;
    float* out_total = out + 3 * plane;

    double* partials = (double*)d_ws;   // NBLOCKS*2 doubles = 50 KB

    bbf_fused<<<NBLOCKS, THREADS, 0, stream>>>(
        lines, rootsx, rootsy, rootsz, ax, ay, az, tarx, tary, w,
        outx, outy, outz, partials);
    bbf_finalize<<<1, 256, 0, stream>>>(lines, partials, out_total);
}

// Round 8
// 94.569 us; speedup vs baseline: 1.4281x; 1.4281x over previous
//
#include <hip/hip_runtime.h>

#define T_TOTAL 200000
#define NL 49
#define NP 50
#define NB 20
#define TB 32                       // timesteps per block; 200000 % 32 == 0
#define THREADS 256                 // 4 waves; each wave owns 8 timesteps
#define NBLK (T_TOTAL / TB)         // 6250
#define TPW 8                       // timesteps per wave

// Phase A: per-wave register tree-prefix (9 ds_bpermute/t) -> positions to LDS.
// Phase B: vectorized float4 loss/reg2/output pass (R3-style).
// LDS ~19.9 KB -> 8 blocks/CU = 32 waves/CU. No delta staging, no tree walks in LDS.
__global__ __launch_bounds__(THREADS, 8) void bbf_fused(
    const float* __restrict__ lines,
    const float* __restrict__ rootsx,
    const float* __restrict__ rootsy,
    const float* __restrict__ rootsz,
    const float* __restrict__ ax,
    const float* __restrict__ ay,
    const float* __restrict__ az,
    const float* __restrict__ tarx,
    const float* __restrict__ tary,
    const float* __restrict__ w,
    float* __restrict__ outx,
    float* __restrict__ outy,
    float* __restrict__ outz,
    double* __restrict__ partials)   // [NBLK][2]: loss, reg2 per block
{
    __shared__ __align__(16) float xs[(TB + 1) * NP + 8];   // +8: phase-B overshoot
    __shared__ __align__(16) float ys[(TB + 1) * NP + 8];
    __shared__ __align__(16) float zs[(TB + 1) * NP + 8];
    __shared__ double redL[THREADS / 64], redR[THREADS / 64];

    const int tid  = threadIdx.x;
    const int lane = tid & 63;
    const int wv   = tid >> 6;
    const int t0   = blockIdx.x * TB;

    const bool isNode = (lane < NP);
    const bool isLimb = (lane >= 1 && lane < NP);

    float Lv = 0.f;
    if (isLimb) Lv = expf(lines[(lane - 1) % NB]);

    // ancestor jump table (pointer jumping: 1st, 2nd, 4th ancestor; root-clamped)
    const int a1 = isLimb ? ((lane - 1) >> 1) : 0;
    const int a2 = (a1 > 0) ? ((a1 - 1) >> 1) : 0;
    const int a3 = (a2 > 0) ? ((a2 - 1) >> 1) : 0;
    const int a4 = (a3 > 0) ? ((a3 - 1) >> 1) : 0;

    // ---- Phase A: wave wv computes t_loc in [8*wv, 8*wv+8) ----
#pragma unroll 4
    for (int k = 0; k < TPW; ++k) {
        const int t_loc = wv * TPW + k;
        const int t = t0 + t_loc;
        float dx = 0.f, dy = 0.f, dz = 0.f;
        if (isLimb) {
            const size_t gi = (size_t)t * NL + (lane - 1);
            const float x = ax[gi], y = ay[gi], z = az[gi];
            const float n = sqrtf(x * x + y * y + z * z) + 1e-10f;
            const float s = Lv / n;
            dx = x * s; dy = y * s; dz = z * s;
        }
        dx += __shfl(dx, a1); dy += __shfl(dy, a1); dz += __shfl(dz, a1);
        dx += __shfl(dx, a2); dy += __shfl(dy, a2); dz += __shfl(dz, a2);
        dx += __shfl(dx, a4); dy += __shfl(dy, a4); dz += __shfl(dz, a4);
        if (isNode) {
            const int o = t_loc * NP + lane;
            xs[o] = dx + rootsx[t];     // t is wave-uniform -> scalar load
            ys[o] = dy + rootsy[t];
            zs[o] = dz + rootsz[t];
        }
    }
    // halo timestep t0+32 (wave 0), skipped by the last block (t0+32 == T)
    if (wv == 0 && t0 + TB < T_TOTAL) {
        const int t = t0 + TB;
        float dx = 0.f, dy = 0.f, dz = 0.f;
        if (isLimb) {
            const size_t gi = (size_t)t * NL + (lane - 1);
            const float x = ax[gi], y = ay[gi], z = az[gi];
            const float n = sqrtf(x * x + y * y + z * z) + 1e-10f;
            const float s = Lv / n;
            dx = x * s; dy = y * s; dz = z * s;
        }
        dx += __shfl(dx, a1); dy += __shfl(dy, a1); dz += __shfl(dz, a1);
        dx += __shfl(dx, a2); dy += __shfl(dy, a2); dz += __shfl(dz, a2);
        dx += __shfl(dx, a4); dy += __shfl(dy, a4); dz += __shfl(dz, a4);
        if (isNode) {
            const int o = TB * NP + lane;
            xs[o] = dx + rootsx[t];
            ys[o] = dy + rootsy[t];
            zs[o] = dz + rootsz[t];
        }
    }
    __syncthreads();

    // ---- Phase B: float4 outputs + loss/reg2 (R3-style vectorized pass) ----
    const size_t gbase = (size_t)t0 * NP;          // blockIdx*1600 floats, 16B aligned
    const float4* tarx4 = (const float4*)(tarx + gbase);
    const float4* tary4 = (const float4*)(tary + gbase);
    const float4* w4    = (const float4*)(w + gbase);
    float4* outx4 = (float4*)(outx + gbase);
    float4* outy4 = (float4*)(outy + gbase);
    float4* outz4 = (float4*)(outz + gbase);

    float lossAcc = 0.f, regAcc = 0.f;
    for (int c = tid; c < (TB * NP) / 4; c += THREADS) {   // 400 float4 groups
        const int j = c << 2;
        const float4 X  = *(const float4*)&xs[j];
        const float4 Y  = *(const float4*)&ys[j];
        const float4 Z  = *(const float4*)&zs[j];
        outx4[c] = X;
        outy4[c] = Y;
        outz4[c] = Z;
        const float4 TX = tarx4[c];
        const float4 TY = tary4[c];
        const float4 WV = w4[c];
        // next-timestep values xs[j+50..j+53] via two aligned b128 reads
        const float4 XA = *(const float4*)&xs[j + 48];
        const float4 XB = *(const float4*)&xs[j + 52];
        const float4 YA = *(const float4*)&ys[j + 48];
        const float4 YB = *(const float4*)&ys[j + 52];
        const float4 ZA = *(const float4*)&zs[j + 48];
        const float4 ZB = *(const float4*)&zs[j + 52];
        const float xv[4] = {X.x, X.y, X.z, X.w};
        const float yv[4] = {Y.x, Y.y, Y.z, Y.w};
        const float zv[4] = {Z.x, Z.y, Z.z, Z.w};
        const float tx[4] = {TX.x, TX.y, TX.z, TX.w};
        const float ty[4] = {TY.x, TY.y, TY.z, TY.w};
        const float wvv[4] = {WV.x, WV.y, WV.z, WV.w};
        const float xn[4] = {XA.z, XA.w, XB.x, XB.y};
        const float yn[4] = {YA.z, YA.w, YB.x, YB.y};
        const float zn[4] = {ZA.z, ZA.w, ZB.x, ZB.y};
#pragma unroll
        for (int e = 0; e < 4; ++e) {
            const float dx = xv[e] - tx[e];
            const float dy = yv[e] - ty[e];
            lossAcc += wvv[e] * (dx * dx + dy * dy);
            const int t = t0 + (j + e) / NP;
            if (t < T_TOTAL - 1) {
                const float ddx = xv[e] - xn[e];
                const float ddy = yv[e] - yn[e];
                const float ddz = zv[e] - zn[e];
                regAcc += ddx * ddx + ddy * ddy + ddz * ddz;
            }
        }
    }

    // wave reduce -> cross-wave LDS -> per-block partial slot
    for (int off = 32; off > 0; off >>= 1) {
        lossAcc += __shfl_down(lossAcc, off);
        regAcc  += __shfl_down(regAcc, off);
    }
    if (lane == 0) { redL[wv] = (double)lossAcc; redR[wv] = (double)regAcc; }
    __syncthreads();
    if (tid == 0) {
        double l = 0.0, r = 0.0;
        for (int i = 0; i < THREADS / 64; ++i) { l += redL[i]; r += redR[i]; }
        partials[2 * (size_t)blockIdx.x]     = l;
        partials[2 * (size_t)blockIdx.x + 1] = r;
    }
}

__global__ __launch_bounds__(256) void bbf_finalize(
    const float* __restrict__ lines,
    const double* __restrict__ partials,
    float* __restrict__ out_total)
{
    __shared__ double rl[4], rr[4];
    const int tid = threadIdx.x;
    double l = 0.0, r = 0.0;
    for (int i = tid; i < NBLK; i += 256) {
        l += partials[2 * (size_t)i];
        r += partials[2 * (size_t)i + 1];
    }
    for (int off = 32; off > 0; off >>= 1) {
        l += __shfl_down(l, off);
        r += __shfl_down(r, off);
    }
    const int wid = tid >> 6;
    if ((tid & 63) == 0) { rl[wid] = l; rr[wid] = r; }
    __syncthreads();
    if (tid == 0) {
        double L = 0.0, R = 0.0;
        for (int i = 0; i < 4; ++i) { L += rl[i]; R += rr[i]; }
        double reg1 = 0.0;
        for (int i = 0; i < NB; ++i) reg1 += (double)expf(lines[i]);
        const double loss = L / ((double)T_TOTAL * (double)NP);
        const double reg2 = R / ((double)(T_TOTAL - 1) * (double)NP);
        *out_total = (float)(loss + 0.001 * reg1 + 0.1 * reg2);
    }
}

extern "C" void kernel_launch(void* const* d_in, const int* in_sizes, int n_in,
                              void* d_out, int out_size, void* d_ws, size_t ws_size,
                              hipStream_t stream) {
    const float* lines  = (const float*)d_in[0];
    const float* rootsx = (const float*)d_in[1];
    const float* rootsy = (const float*)d_in[2];
    const float* rootsz = (const float*)d_in[3];
    const float* ax     = (const float*)d_in[4];
    const float* ay     = (const float*)d_in[5];
    const float* az     = (const float*)d_in[6];
    const float* tarx   = (const float*)d_in[7];
    const float* tary   = (const float*)d_in[8];
    const float* w      = (const float*)d_in[9];

    float* out = (float*)d_out;
    const size_t plane = (size_t)T_TOTAL * NP;
    float* outx = out;
    float* outy = out + plane;
    float* outz = out + 2 * plane;
    float* out_total = out + 3 * plane;

    double* partials = (double*)d_ws;   // NBLK*2 doubles = 100 KB

    bbf_fused<<<NBLK, THREADS, 0, stream>>>(
        lines, rootsx, rootsy, rootsz, ax, ay, az, tarx, tary, w,
        outx, outy, outz, partials);
    bbf_finalize<<<1, 256, 0, stream>>>(lines, partials, out_total);
}

// Round 9
// 83.129 us; speedup vs baseline: 1.6246x; 1.1376x over previous
//
#include <hip/hip_runtime.h>

#define T_TOTAL 200000
#define NL 49
#define NP 50
#define NB 20
#define TB 32                       // timesteps per block; 200000 % 32 == 0
#define THREADS 256                 // 4 waves; each wave owns 8 timesteps
#define NBLK (T_TOTAL / TB)         // 6250
#define TPW 8                       // timesteps per wave

// Phase A: per-wave register tree-prefix. Loads for all 8 timesteps issued
// UNCONDITIONALLY and up-front (clamped lane index, masked by Lv=0) so the
// wave has ~24 loads in flight (MLP), then 8 independent shuffle-prefix
// chains -> positions to LDS. Phase B: float4 loss/reg2/output pass.
__global__ __launch_bounds__(THREADS, 8) void bbf_fused(
    const float* __restrict__ lines,
    const float* __restrict__ rootsx,
    const float* __restrict__ rootsy,
    const float* __restrict__ rootsz,
    const float* __restrict__ ax,
    const float* __restrict__ ay,
    const float* __restrict__ az,
    const float* __restrict__ tarx,
    const float* __restrict__ tary,
    const float* __restrict__ w,
    float* __restrict__ outx,
    float* __restrict__ outy,
    float* __restrict__ outz,
    double* __restrict__ partials)   // [NBLK][2]: loss, reg2 per block
{
    __shared__ __align__(16) float xs[(TB + 1) * NP + 8];   // +8: phase-B overshoot
    __shared__ __align__(16) float ys[(TB + 1) * NP + 8];
    __shared__ __align__(16) float zs[(TB + 1) * NP + 8];
    __shared__ double redL[THREADS / 64], redR[THREADS / 64];

    const int tid  = threadIdx.x;
    const int lane = tid & 63;
    const int wv   = tid >> 6;
    const int t0   = blockIdx.x * TB;

    const bool isNode = (lane < NP);
    const bool isLimb = (lane >= 1 && lane < NP);
    const int  li     = isLimb ? (lane - 1) : 0;    // clamped limb index (valid addr)

    const float Lv = isLimb ? expf(lines[li % NB]) : 0.f;   // 0 masks non-limb lanes

    // ancestor jump table (pointer jumping: 1st, 2nd, 4th ancestor; root-clamped)
    const int a1 = isLimb ? ((lane - 1) >> 1) : 0;
    const int a2 = (a1 > 0) ? ((a1 - 1) >> 1) : 0;
    const int a3 = (a2 > 0) ? ((a2 - 1) >> 1) : 0;
    const int a4 = (a3 > 0) ? ((a3 - 1) >> 1) : 0;

    // ---- Phase A1: issue ALL angle loads for this wave's 8 timesteps ----
    float xa[TPW], ya[TPW], za[TPW];
#pragma unroll
    for (int k = 0; k < TPW; ++k) {
        const int t = t0 + wv * TPW + k;
        const size_t gi = (size_t)t * NL + li;
        xa[k] = ax[gi];
        ya[k] = ay[gi];
        za[k] = az[gi];
    }

    // ---- Phase A2: 8 independent prefix chains -> LDS positions ----
#pragma unroll
    for (int k = 0; k < TPW; ++k) {
        const int t_loc = wv * TPW + k;
        const int t = t0 + t_loc;
        const float x = xa[k], y = ya[k], z = za[k];
        const float n = sqrtf(x * x + y * y + z * z) + 1e-10f;
        const float s = Lv / n;                    // 0 for non-limb lanes
        float dx = x * s, dy = y * s, dz = z * s;
        dx += __shfl(dx, a1); dy += __shfl(dy, a1); dz += __shfl(dz, a1);
        dx += __shfl(dx, a2); dy += __shfl(dy, a2); dz += __shfl(dz, a2);
        dx += __shfl(dx, a4); dy += __shfl(dy, a4); dz += __shfl(dz, a4);
        if (isNode) {
            const int o = t_loc * NP + lane;
            xs[o] = dx + rootsx[t];                // t wave-uniform -> s_load
            ys[o] = dy + rootsy[t];
            zs[o] = dz + rootsz[t];
        }
    }

    // halo timestep t0+32 (wave 0), skipped by the last block (t0+32 == T)
    if (wv == 0 && t0 + TB < T_TOTAL) {
        const int t = t0 + TB;
        const size_t gi = (size_t)t * NL + li;
        const float x = ax[gi], y = ay[gi], z = az[gi];
        const float n = sqrtf(x * x + y * y + z * z) + 1e-10f;
        const float s = Lv / n;
        float dx = x * s, dy = y * s, dz = z * s;
        dx += __shfl(dx, a1); dy += __shfl(dy, a1); dz += __shfl(dz, a1);
        dx += __shfl(dx, a2); dy += __shfl(dy, a2); dz += __shfl(dz, a2);
        dx += __shfl(dx, a4); dy += __shfl(dy, a4); dz += __shfl(dz, a4);
        if (isNode) {
            const int o = TB * NP + lane;
            xs[o] = dx + rootsx[t];
            ys[o] = dy + rootsy[t];
            zs[o] = dz + rootsz[t];
        }
    }
    __syncthreads();

    // ---- Phase B: float4 outputs + loss/reg2 ----
    const size_t gbase = (size_t)t0 * NP;          // blockIdx*1600 floats, 16B aligned
    const float4* tarx4 = (const float4*)(tarx + gbase);
    const float4* tary4 = (const float4*)(tary + gbase);
    const float4* w4    = (const float4*)(w + gbase);
    float4* outx4 = (float4*)(outx + gbase);
    float4* outy4 = (float4*)(outy + gbase);
    float4* outz4 = (float4*)(outz + gbase);

    float lossAcc = 0.f, regAcc = 0.f;
    for (int c = tid; c < (TB * NP) / 4; c += THREADS) {   // 400 float4 groups
        const int j = c << 2;
        const float4 X  = *(const float4*)&xs[j];
        const float4 Y  = *(const float4*)&ys[j];
        const float4 Z  = *(const float4*)&zs[j];
        outx4[c] = X;
        outy4[c] = Y;
        outz4[c] = Z;
        const float4 TX = tarx4[c];
        const float4 TY = tary4[c];
        const float4 WV = w4[c];
        // next-timestep values xs[j+50..j+53] via two aligned b128 reads
        const float4 XA = *(const float4*)&xs[j + 48];
        const float4 XB = *(const float4*)&xs[j + 52];
        const float4 YA = *(const float4*)&ys[j + 48];
        const float4 YB = *(const float4*)&ys[j + 52];
        const float4 ZA = *(const float4*)&zs[j + 48];
        const float4 ZB = *(const float4*)&zs[j + 52];
        const float xv[4] = {X.x, X.y, X.z, X.w};
        const float yv[4] = {Y.x, Y.y, Y.z, Y.w};
        const float zv[4] = {Z.x, Z.y, Z.z, Z.w};
        const float tx[4] = {TX.x, TX.y, TX.z, TX.w};
        const float ty[4] = {TY.x, TY.y, TY.z, TY.w};
        const float wvv[4] = {WV.x, WV.y, WV.z, WV.w};
        const float xn[4] = {XA.z, XA.w, XB.x, XB.y};
        const float yn[4] = {YA.z, YA.w, YB.x, YB.y};
        const float zn[4] = {ZA.z, ZA.w, ZB.x, ZB.y};
#pragma unroll
        for (int e = 0; e < 4; ++e) {
            const float dx = xv[e] - tx[e];
            const float dy = yv[e] - ty[e];
            lossAcc += wvv[e] * (dx * dx + dy * dy);
            const int t = t0 + (j + e) / NP;
            if (t < T_TOTAL - 1) {
                const float ddx = xv[e] - xn[e];
                const float ddy = yv[e] - yn[e];
                const float ddz = zv[e] - zn[e];
                regAcc += ddx * ddx + ddy * ddy + ddz * ddz;
            }
        }
    }

    // wave reduce -> cross-wave LDS -> per-block partial slot
    for (int off = 32; off > 0; off >>= 1) {
        lossAcc += __shfl_down(lossAcc, off);
        regAcc  += __shfl_down(regAcc, off);
    }
    if (lane == 0) { redL[wv] = (double)lossAcc; redR[wv] = (double)regAcc; }
    __syncthreads();
    if (tid == 0) {
        double l = 0.0, r = 0.0;
        for (int i = 0; i < THREADS / 64; ++i) { l += redL[i]; r += redR[i]; }
        partials[2 * (size_t)blockIdx.x]     = l;
        partials[2 * (size_t)blockIdx.x + 1] = r;
    }
}

__global__ __launch_bounds__(256) void bbf_finalize(
    const float* __restrict__ lines,
    const double* __restrict__ partials,
    float* __restrict__ out_total)
{
    __shared__ double rl[4], rr[4];
    const int tid = threadIdx.x;
    double l = 0.0, r = 0.0;
    for (int i = tid; i < NBLK; i += 256) {
        l += partials[2 * (size_t)i];
        r += partials[2 * (size_t)i + 1];
    }
    for (int off = 32; off > 0; off >>= 1) {
        l += __shfl_down(l, off);
        r += __shfl_down(r, off);
    }
    const int wid = tid >> 6;
    if ((tid & 63) == 0) { rl[wid] = l; rr[wid] = r; }
    __syncthreads();
    if (tid == 0) {
        double L = 0.0, R = 0.0;
        for (int i = 0; i < 4; ++i) { L += rl[i]; R += rr[i]; }
        double reg1 = 0.0;
        for (int i = 0; i < NB; ++i) reg1 += (double)expf(lines[i]);
        const double loss = L / ((double)T_TOTAL * (double)NP);
        const double reg2 = R / ((double)(T_TOTAL - 1) * (double)NP);
        *out_total = (float)(loss + 0.001 * reg1 + 0.1 * reg2);
    }
}

extern "C" void kernel_launch(void* const* d_in, const int* in_sizes, int n_in,
                              void* d_out, int out_size, void* d_ws, size_t ws_size,
                              hipStream_t stream) {
    const float* lines  = (const float*)d_in[0];
    const float* rootsx = (const float*)d_in[1];
    const float* rootsy = (const float*)d_in[2];
    const float* rootsz = (const float*)d_in[3];
    const float* ax     = (const float*)d_in[4];
    const float* ay     = (const float*)d_in[5];
    const float* az     = (const float*)d_in[6];
    const float* tarx   = (const float*)d_in[7];
    const float* tary   = (const float*)d_in[8];
    const float* w      = (const float*)d_in[9];

    float* out = (float*)d_out;
    const size_t plane = (size_t)T_TOTAL * NP;
    float* outx = out;
    float* outy = out + plane;
    float* outz = out + 2 * plane;
    float* out_total = out + 3 * plane;

    double* partials = (double*)d_ws;   // NBLK*2 doubles = 100 KB

    bbf_fused<<<NBLK, THREADS, 0, stream>>>(
        lines, rootsx, rootsy, rootsz, ax, ay, az, tarx, tary, w,
        outx, outy, outz, partials);
    bbf_finalize<<<1, 256, 0, stream>>>(lines, partials, out_total);
}